// Round 2
// baseline (467.570 us; speedup 1.0000x reference)
//
#include <hip/hip_runtime.h>
#include <hip/hip_bf16.h>

// LSTM cell: B=4096, IN=1024, H=2048.
// gates = [prev_h | x] @ [W_i;W_f;W_o;W_c]^T  -> [4096, 8192]
// Pipeline: pack fp32->bf16, m97-style 128x128 MFMA GEMM-BT (bf16 in, bf16 gates out),
// fused elementwise LSTM epilogue writing FP32 next_h / next_c (d_out is float*).

#define BATCH 4096
#define INW   1024
#define HID   2048
#define GK    3072   // HID + INW
#define GN    8192   // 4*HID

typedef __attribute__((ext_vector_type(8))) short short8;
typedef __attribute__((ext_vector_type(4))) float floatx4;

__device__ __forceinline__ unsigned short f2bf(float f) {
    union { float f; unsigned u; } v; v.f = f;
    unsigned r = v.u + 0x7FFFu + ((v.u >> 16) & 1u);
    return (unsigned short)(r >> 16);
}
__device__ __forceinline__ float bf2f(unsigned short u) {
    union { unsigned u; float f; } v; v.u = ((unsigned)u) << 16;
    return v.f;
}
__device__ __forceinline__ float sigf(float x) {
    return 1.0f / (1.0f + __expf(-x));
}
__device__ __forceinline__ float tanhfast(float x) {
    float t = __expf(fminf(fmaxf(2.0f * x, -30.0f), 30.0f));
    return (t - 1.0f) / (t + 1.0f);
}

// ---- fp32 -> bf16 pack with row restride (src contiguous [rows][src_w4*4]) ----
__global__ __launch_bounds__(256) void cvt_bf16(const float4* __restrict__ src,
                                                unsigned short* __restrict__ dst,
                                                int src_w4, int dst_stride, int n4) {
    int i = blockIdx.x * 256 + threadIdx.x;
    if (i >= n4) return;
    int row = i / src_w4;
    int c4  = i - row * src_w4;
    float4 v = src[i];
    ushort4 o;
    o.x = f2bf(v.x); o.y = f2bf(v.y); o.z = f2bf(v.z); o.w = f2bf(v.w);
    *(ushort4*)&dst[(size_t)row * dst_stride + (size_t)c4 * 4] = o;
}

__device__ __forceinline__ void gld16(const unsigned short* g, unsigned short* l) {
    __builtin_amdgcn_global_load_lds((const __attribute__((address_space(1))) unsigned int*)g,
                                     (__attribute__((address_space(3))) unsigned int*)l,
                                     16, 0, 0);
}

// ---- C[M,N] = A[M,K] * Bt[N,K]^T  (bf16 in, bf16 out, fp32 accumulate) ----
__global__ __launch_bounds__(256) void gemm_bt(const unsigned short* __restrict__ A,
                                               const unsigned short* __restrict__ Bt,
                                               unsigned short* __restrict__ C) {
    __shared__ unsigned short lA[128 * 32];  // 8 KB
    __shared__ unsigned short lB[128 * 32];  // 8 KB
    const int tid  = threadIdx.x;
    const int wave = tid >> 6;
    const int lane = tid & 63;
    const long row0 = (long)blockIdx.x * 128;   // M tile
    const long col0 = (long)blockIdx.y * 128;   // N tile

    // staging: thread t stages 16B = 8 bf16 -> LDS byte offset t*16 == row (t/4), k-chunk (t%4)*8
    const int sr = tid >> 2;
    const int sk = (tid & 3) << 3;
    const unsigned short* gA0 = A  + (row0 + sr)      * GK + sk;
    const unsigned short* gA1 = A  + (row0 + 64 + sr) * GK + sk;
    const unsigned short* gB0 = Bt + (col0 + sr)      * GK + sk;
    const unsigned short* gB1 = Bt + (col0 + 64 + sr) * GK + sk;
    unsigned short* lA0 = &lA[wave * 512];
    unsigned short* lA1 = &lA[2048 + wave * 512];
    unsigned short* lB0 = &lB[wave * 512];
    unsigned short* lB1 = &lB[2048 + wave * 512];

    floatx4 acc[4][4];
    #pragma unroll
    for (int mi = 0; mi < 4; mi++)
        #pragma unroll
        for (int ni = 0; ni < 4; ni++)
            acc[mi][ni] = (floatx4)(0.0f);

    // wave -> 64x64 quadrant; lane fragment indices
    const int mBase = (wave >> 1) << 6;
    const int nBase = (wave & 1) << 6;
    const int fr = lane & 15;            // A/B fragment row (m or n)
    const int kq = (lane >> 4) << 3;     // k chunk within BK=32

    for (int k0 = 0; k0 < GK; k0 += 32) {
        __syncthreads();
        gld16(gA0 + k0, lA0);
        gld16(gA1 + k0, lA1);
        gld16(gB0 + k0, lB0);
        gld16(gB1 + k0, lB1);
        __syncthreads();

        short8 af[4], bfv[4];
        #pragma unroll
        for (int mi = 0; mi < 4; mi++)
            af[mi] = *(const short8*)&lA[(mBase + mi * 16 + fr) * 32 + kq];
        #pragma unroll
        for (int ni = 0; ni < 4; ni++)
            bfv[ni] = *(const short8*)&lB[(nBase + ni * 16 + fr) * 32 + kq];
        #pragma unroll
        for (int mi = 0; mi < 4; mi++)
            #pragma unroll
            for (int ni = 0; ni < 4; ni++)
                acc[mi][ni] = __builtin_amdgcn_mfma_f32_16x16x32_bf16(af[mi], bfv[ni], acc[mi][ni], 0, 0, 0);
    }

    // C/D layout: col = lane&15, row = (lane>>4)*4 + reg  [m89-verified]
    const int cr = (lane >> 4) << 2;
    const int cc = lane & 15;
    #pragma unroll
    for (int mi = 0; mi < 4; mi++) {
        #pragma unroll
        for (int ni = 0; ni < 4; ni++) {
            long base = (row0 + mBase + mi * 16 + cr) * (long)GN + col0 + nBase + ni * 16 + cc;
            #pragma unroll
            for (int r = 0; r < 4; r++)
                C[base + (long)r * GN] = f2bf(acc[mi][ni][r]);
        }
    }
}

// ---- LSTM elementwise epilogue: gates[B,4H] bf16 (i,f,o,c slabs) -> FP32 next_h, next_c ----
__global__ __launch_bounds__(256) void lstm_ep(const unsigned short* __restrict__ gates,
                                               const float* __restrict__ prev_c,
                                               float* __restrict__ out) {
    const int i = blockIdx.x * 256 + threadIdx.x;     // one per 4 elements of B*H
    const int b = i >> 9;                             // H/4 = 512 groups per row
    const int h = (i & 511) << 2;
    const size_t gb = (size_t)b * GN + h;
    ushort4 gi = *(const ushort4*)&gates[gb];
    ushort4 gf = *(const ushort4*)&gates[gb + HID];
    ushort4 go = *(const ushort4*)&gates[gb + 2 * HID];
    ushort4 gc = *(const ushort4*)&gates[gb + 3 * HID];
    const size_t ob = (size_t)b * HID + h;
    float4 c4 = *(const float4*)&prev_c[ob];

    unsigned short giv[4] = {gi.x, gi.y, gi.z, gi.w};
    unsigned short gfv[4] = {gf.x, gf.y, gf.z, gf.w};
    unsigned short gov[4] = {go.x, go.y, go.z, go.w};
    unsigned short gcv[4] = {gc.x, gc.y, gc.z, gc.w};
    float cv[4] = {c4.x, c4.y, c4.z, c4.w};
    float nh[4], nc[4];
    #pragma unroll
    for (int j = 0; j < 4; j++) {
        float vi = sigf(bf2f(giv[j]));
        float vf = sigf(bf2f(gfv[j]));
        float vo = sigf(bf2f(gov[j]));
        float vc = tanhfast(bf2f(gcv[j]));
        float ncf = vf * cv[j] + vi * vc;
        float nhf = vo * tanhfast(ncf);
        nc[j] = ncf;
        nh[j] = nhf;
    }
    float4 vh = {nh[0], nh[1], nh[2], nh[3]};
    float4 vc4 = {nc[0], nc[1], nc[2], nc[3]};
    *(float4*)&out[ob] = vh;                                 // next_h (fp32)
    *(float4*)&out[(size_t)BATCH * HID + ob] = vc4;          // next_c (fp32)
}

extern "C" void kernel_launch(void* const* d_in, const int* in_sizes, int n_in,
                              void* d_out, int out_size, void* d_ws, size_t ws_size,
                              hipStream_t stream) {
    const float* x   = (const float*)d_in[0];
    const float* ph  = (const float*)d_in[1];
    const float* pc  = (const float*)d_in[2];
    const float* Wi  = (const float*)d_in[3];
    const float* Wf  = (const float*)d_in[4];
    const float* Wo  = (const float*)d_in[5];
    const float* Wc  = (const float*)d_in[6];

    // workspace layout (bf16): hx [4096,3072] | W [8192,3072] | gates [4096,8192]  (~143 MB)
    unsigned short* hx    = (unsigned short*)d_ws;
    unsigned short* Wb    = hx + (size_t)BATCH * GK;
    unsigned short* gates = Wb + (size_t)GN * GK;
    float* out = (float*)d_out;

    // pack hx = [prev_h | x] -> bf16, row stride GK
    cvt_bf16<<<8192, 256, 0, stream>>>((const float4*)ph, hx,       HID / 4, GK, BATCH * (HID / 4));
    cvt_bf16<<<4096, 256, 0, stream>>>((const float4*)x,  hx + HID, INW / 4, GK, BATCH * (INW / 4));
    // pack W stacked [Wi;Wf;Wo;Wc] -> bf16 (contiguous rows of length GK)
    cvt_bf16<<<6144, 256, 0, stream>>>((const float4*)Wi, Wb,                        GK / 4, GK, HID * (GK / 4));
    cvt_bf16<<<6144, 256, 0, stream>>>((const float4*)Wf, Wb + (size_t)HID * GK,     GK / 4, GK, HID * (GK / 4));
    cvt_bf16<<<6144, 256, 0, stream>>>((const float4*)Wo, Wb + (size_t)2 * HID * GK, GK / 4, GK, HID * (GK / 4));
    cvt_bf16<<<6144, 256, 0, stream>>>((const float4*)Wc, Wb + (size_t)3 * HID * GK, GK / 4, GK, HID * (GK / 4));

    // gates = hx @ W^T   [4096, 8192]
    gemm_bt<<<dim3(BATCH / 128, GN / 128), 256, 0, stream>>>(hx, Wb, gates);

    // elementwise LSTM -> fp32 outputs
    lstm_ep<<<(BATCH * HID / 4) / 256, 256, 0, stream>>>(gates, pc, out);
}